// Round 11
// baseline (457.199 us; speedup 1.0000x reference)
//
#include <hip/hip_runtime.h>

typedef __attribute__((ext_vector_type(8))) short short8;
typedef __attribute__((ext_vector_type(4))) float f32x4;

#define SCHUNK 2048   // elements per scan block (256 threads x 8)
#define MAXN   20480  // LDS histogram capacity (n = 20000)
#define NSLICE 8      // feature slices (32 floats each) -> XCD pinning
#define NPB    40     // nodes per pull block chunk (10 per wave)

// ---------------------------------------------------------------- bf16 split helpers
__device__ inline unsigned short f2bf(float v) {
    unsigned u = __float_as_uint(v);
    u += 0x7FFFu + ((u >> 16) & 1u);   // RNE
    return (unsigned short)(u >> 16);
}
__device__ inline float bf2f(unsigned short h) {
    return __uint_as_float((unsigned)h << 16);
}

// ---------------------------------------------------------------- bias sums
__global__ void bias_sum_kernel(const float* __restrict__ b1s, const float* __restrict__ b1u,
                                const float* __restrict__ b2s, const float* __restrict__ b2u,
                                float* __restrict__ bsum1, float* __restrict__ bsum2) {
    int i = threadIdx.x;
    bsum1[i] = b1s[i] + b1u[i];
    bsum2[i] = b2s[i] + b2u[i];
}

// ---------------------------------------------------------------- W prep: fragment-packed bf16 split
// Bpk layout: [ntile(16)][kstep(16)][plane(2)][lane(64)][8] shorts.
__global__ void wprep_kernel(const float* __restrict__ W1s, const float* __restrict__ W1u,
                             const float* __restrict__ W2s, const float* __restrict__ W2u,
                             unsigned short* __restrict__ Bpk1, unsigned short* __restrict__ Bpk2) {
    int k = blockIdx.x;        // 0..511
    int nn = threadIdx.x;      // 0..255
    int layer = blockIdx.y;
    const float* Ws = layer ? W2s : W1s;
    const float* Wu = layer ? W2u : W1u;
    float w = (k < 256) ? Ws[k * 256 + nn] : Wu[(k - 256) * 256 + nn];
    unsigned short hi = f2bf(w);
    unsigned short lo = f2bf(w - bf2f(hi));
    unsigned short* B = layer ? Bpk2 : Bpk1;
    size_t frag = ((size_t)(nn >> 4) * 16 + (k >> 5)) * 2;           // *2 planes
    size_t addr = frag * 512 + ((nn & 15) + ((k >> 3) & 3) * 16) * 8 + (k & 7);
    B[addr] = hi;          // plane 0
    B[addr + 512] = lo;    // plane 1
}

// ---------------------------------------------------------------- phase H: per-block packed histograms
__global__ __launch_bounds__(256) void hist_kernel(
    const int* __restrict__ sS, const int* __restrict__ dS,
    const int* __restrict__ sU, const int* __restrict__ dU,
    int Es, int Eu, int n, int nblk, unsigned int* __restrict__ histG) {
    __shared__ unsigned int h[MAXN];
    const int rel = blockIdx.y;
    const int* src = rel ? sU : sS;
    const int* dst = rel ? dU : dS;
    int E = rel ? Eu : Es;
    int b = blockIdx.x;
    int chunk = (E + nblk - 1) / nblk;
    int beg = b * chunk;
    int end = min(E, beg + chunk);
    for (int i = threadIdx.x; i < n; i += 256) h[i] = 0u;
    __syncthreads();
    for (int i = beg + threadIdx.x; i < end; i += 256) {
        atomicAdd(&h[src[i]], 1u);
        atomicAdd(&h[dst[i]], 0x10000u);
    }
    __syncthreads();
    unsigned int* out = histG + ((size_t)rel * nblk + b) * n;
    for (int i = threadIdx.x; i < n; i += 256) out[i] = h[i];
}

// ---------------------------------------------------------------- phase B1: totals -> scales + deg_in
// Unrolled x8: 8 independent strided loads in flight.
__global__ void totals_kernel(const unsigned int* __restrict__ histG, int n, int nblk,
                              float* __restrict__ sOutS, float* __restrict__ sInS,
                              float* __restrict__ sOutU, float* __restrict__ sInU,
                              int* __restrict__ degInS, int* __restrict__ degInU) {
    const int rel = blockIdx.y;
    int i = blockIdx.x * 256 + threadIdx.x;
    if (i >= n) return;
    const unsigned int* hg = histG + (size_t)rel * nblk * n + i;
    unsigned int lo = 0, hi = 0;
    int b = 0;
    for (; b + 8 <= nblk; b += 8) {
        unsigned v0 = hg[(size_t)(b + 0) * n];
        unsigned v1 = hg[(size_t)(b + 1) * n];
        unsigned v2 = hg[(size_t)(b + 2) * n];
        unsigned v3 = hg[(size_t)(b + 3) * n];
        unsigned v4 = hg[(size_t)(b + 4) * n];
        unsigned v5 = hg[(size_t)(b + 5) * n];
        unsigned v6 = hg[(size_t)(b + 6) * n];
        unsigned v7 = hg[(size_t)(b + 7) * n];
        lo += (v0 & 0xFFFFu) + (v1 & 0xFFFFu) + (v2 & 0xFFFFu) + (v3 & 0xFFFFu)
            + (v4 & 0xFFFFu) + (v5 & 0xFFFFu) + (v6 & 0xFFFFu) + (v7 & 0xFFFFu);
        hi += (v0 >> 16) + (v1 >> 16) + (v2 >> 16) + (v3 >> 16)
            + (v4 >> 16) + (v5 >> 16) + (v6 >> 16) + (v7 >> 16);
    }
    for (; b < nblk; ++b) {
        unsigned v = hg[(size_t)b * n];
        lo += v & 0xFFFFu;
        hi += v >> 16;
    }
    float so = rsqrtf((float)(lo > 1u ? lo : 1u));
    float si = rsqrtf((float)(hi > 1u ? hi : 1u));
    if (rel) { sOutU[i] = so; sInU[i] = si; degInU[i] = (int)hi; }
    else     { sOutS[i] = so; sInS[i] = si; degInS[i] = (int)hi; }
}

// ---------------------------------------------------------------- scan phase 1
__global__ __launch_bounds__(256) void scan_part_kernel(const int* __restrict__ degA,
                                                        const int* __restrict__ degB,
                                                        int n, int NB, int* __restrict__ bsum) {
    const int rel = blockIdx.y;
    const int* deg = rel ? degB : degA;
    int t = threadIdx.x;
    int base = blockIdx.x * SCHUNK + t * 8;
    int s = 0;
    if (base + 8 <= n) {
        int4 a = *(const int4*)(deg + base);
        int4 b = *(const int4*)(deg + base + 4);
        s = a.x + a.y + a.z + a.w + b.x + b.y + b.z + b.w;
    } else {
        for (int i = 0; i < 8; ++i)
            if (base + i < n) s += deg[base + i];
    }
    __shared__ int sm[256];
    sm[t] = s;
    __syncthreads();
    for (int off = 128; off > 0; off >>= 1) {
        if (t < off) sm[t] += sm[t + off];
        __syncthreads();
    }
    if (t == 0) bsum[rel * NB + blockIdx.x] = sm[0];
}

// ---------------------------------------------------------------- scan phase 2
__global__ void scan_mid_kernel(int* __restrict__ bsum, int NB,
                                int* __restrict__ rpA, int* __restrict__ rpB, int n) {
    int t = threadIdx.x;
    if (t >= 2) return;
    int* bs = bsum + t * NB;
    int run = 0;
    for (int i = 0; i < NB; ++i) {
        int v = bs[i];
        bs[i] = run;
        run += v;
    }
    int* rp = t ? rpB : rpA;
    rp[n] = run;
}

// ---------------------------------------------------------------- scan phase 3
__global__ __launch_bounds__(256) void scan_final_kernel(const int* __restrict__ degA,
                                                         const int* __restrict__ degB,
                                                         const int* __restrict__ bsum,
                                                         int n, int NB,
                                                         int* __restrict__ rpA,
                                                         int* __restrict__ rpB) {
    const int rel = blockIdx.y;
    const int* deg = rel ? degB : degA;
    int* rp = rel ? rpB : rpA;
    int t = threadIdx.x;
    int base = blockIdx.x * SCHUNK + t * 8;
    int v[8];
    if (base + 8 <= n) {
        int4 a = *(const int4*)(deg + base);
        int4 b = *(const int4*)(deg + base + 4);
        v[0] = a.x; v[1] = a.y; v[2] = a.z; v[3] = a.w;
        v[4] = b.x; v[5] = b.y; v[6] = b.z; v[7] = b.w;
    } else {
        for (int i = 0; i < 8; ++i) v[i] = (base + i < n) ? deg[base + i] : 0;
    }
    int s = 0;
    #pragma unroll
    for (int i = 0; i < 8; ++i) s += v[i];
    __shared__ int sm[256];
    sm[t] = s;
    __syncthreads();
    #pragma unroll
    for (int off = 1; off < 256; off <<= 1) {
        int y = (t >= off) ? sm[t - off] : 0;
        __syncthreads();
        sm[t] += y;
        __syncthreads();
    }
    int run = bsum[rel * NB + blockIdx.x] + sm[t] - s;
    #pragma unroll
    for (int i = 0; i < 8; ++i) {
        if (base + i < n) rp[base + i] = run;
        run += v[i];
    }
}

// ---------------------------------------------------------------- phase B2: per-block scatter offsets
__global__ void offsets_kernel(const unsigned int* __restrict__ histG,
                               const int* __restrict__ rpS, const int* __restrict__ rpU,
                               int n, int nblk, int* __restrict__ offsG) {
    const int rel = blockIdx.y;
    int i = blockIdx.x * 256 + threadIdx.x;
    if (i >= n) return;
    const unsigned int* hg = histG + (size_t)rel * nblk * n + i;
    int* og = offsG + (size_t)rel * nblk * n + i;
    int run = (rel ? rpU : rpS)[i];
    int b = 0;
    for (; b + 8 <= nblk; b += 8) {
        unsigned v0 = hg[(size_t)(b + 0) * n];
        unsigned v1 = hg[(size_t)(b + 1) * n];
        unsigned v2 = hg[(size_t)(b + 2) * n];
        unsigned v3 = hg[(size_t)(b + 3) * n];
        unsigned v4 = hg[(size_t)(b + 4) * n];
        unsigned v5 = hg[(size_t)(b + 5) * n];
        unsigned v6 = hg[(size_t)(b + 6) * n];
        unsigned v7 = hg[(size_t)(b + 7) * n];
        og[(size_t)(b + 0) * n] = run; run += (int)(v0 >> 16);
        og[(size_t)(b + 1) * n] = run; run += (int)(v1 >> 16);
        og[(size_t)(b + 2) * n] = run; run += (int)(v2 >> 16);
        og[(size_t)(b + 3) * n] = run; run += (int)(v3 >> 16);
        og[(size_t)(b + 4) * n] = run; run += (int)(v4 >> 16);
        og[(size_t)(b + 5) * n] = run; run += (int)(v5 >> 16);
        og[(size_t)(b + 6) * n] = run; run += (int)(v6 >> 16);
        og[(size_t)(b + 7) * n] = run; run += (int)(v7 >> 16);
    }
    for (; b < nblk; ++b) {
        unsigned v = hg[(size_t)b * n];
        og[(size_t)b * n] = run;
        run += (int)(v >> 16);
    }
}

// ---------------------------------------------------------------- phase C: CSR scatter, packed (u, w)
__global__ __launch_bounds__(256) void csr_scatter_kernel(
    const int* __restrict__ sS, const int* __restrict__ dS,
    const int* __restrict__ sU, const int* __restrict__ dU,
    int Es, int Eu, int n, int nblk, const int* __restrict__ offsG,
    const float* __restrict__ sOutS, const float* __restrict__ sOutU,
    int2* __restrict__ csrPS, int2* __restrict__ csrPU) {
    __shared__ int off[MAXN];
    const int rel = blockIdx.y;
    const int* src = rel ? sU : sS;
    const int* dst = rel ? dU : dS;
    const float* so = rel ? sOutU : sOutS;
    int2* csrP = rel ? csrPU : csrPS;
    int E = rel ? Eu : Es;
    int b = blockIdx.x;
    int chunk = (E + nblk - 1) / nblk;  // MUST match hist_kernel
    int beg = b * chunk;
    int end = min(E, beg + chunk);
    const int* og = offsG + ((size_t)rel * nblk + b) * n;
    for (int i = threadIdx.x; i < n; i += 256) off[i] = og[i];
    __syncthreads();
    for (int i = beg + threadIdx.x; i < end; i += 256) {
        int s = src[i];
        int pos = atomicAdd(&off[dst[i]], 1);
        csrP[pos] = make_int2(s, __float_as_int(so[s]));
    }
}

// ---------------------------------------------------------------- sliced pull aggregation
// block = (chunk, rel, slice); slice = blockIdx.x & 7 pins slice -> XCD (2.56 MB/XCD L2).
// Wave: one node at a time; 8 subgroups x 8 lanes. Edge batch (<=64) staged in
// wave-private LDS: one ds_read_b64 per edge replaces 2 bpermutes, and the NEXT
// node's rp+csrP fetch is issued during the CURRENT node's gather/FMA phase
// (cross-node software pipeline; single LDS buffer is safe because same-wave DS
// ops execute in order: the staging write follows the last consume read).
// deg>64 spill batches use the register+shfl path (rare, Poisson(32)).
__global__ __launch_bounds__(256) void pull_slice_kernel(
    const float4* __restrict__ xin,      // [n][64] float4
    const int2* __restrict__ csrPS, const int2* __restrict__ csrPU,
    const int* __restrict__ rpS, const int* __restrict__ rpU,
    const float* __restrict__ sinS, const float* __restrict__ sinU,
    unsigned short* __restrict__ aggPk, int n) {
    __shared__ int2 elds[4][64];   // per-wave 64-edge staging
    int bid = blockIdx.x;
    int slice = bid & (NSLICE - 1);
    int rest = bid >> 3;
    int rel = rest & 1;
    int chunk = rest >> 1;
    const int2* csrP = rel ? csrPU : csrPS;
    const int* rp = rel ? rpU : rpS;
    const float* sinv = rel ? sinU : sinS;

    int wave = threadIdx.x >> 6;
    int lane = threadIdx.x & 63;
    int sub = lane >> 3;          // 0..7 edge slot
    int sl = lane & 7;            // float4 index within slice
    int fbase = slice * 8 + sl;   // float4 index within a 64-float4 row
    int kstepg = rel * 8 + slice;

    int start = chunk * NPB;
    int lim = min(n, start + NPB);
    int node = start + wave;
    if (node >= lim) return;      // no barriers below: early exit is safe

    // prologue: stage first node's first batch
    int beg = rp[node], end = rp[node + 1];
    {
        int cnt = min(end - beg, 64);
        int2 p = make_int2(0, 0);
        if (lane < cnt) p = csrP[beg + lane];
        elds[wave][lane] = p;
    }
    const int2* ebase = &elds[wave][sub];   // + j*8 walks edge j of this subgroup

    while (node < lim) {
        int next = node + 4;
        // ---- prefetch next node's meta + edge batch (overlaps current compute)
        int nbeg = 0, nend = 0;
        int2 np = make_int2(0, 0);
        if (next < lim) {
            nbeg = rp[next];
            nend = rp[next + 1];
            int ncnt = min(nend - nbeg, 64);
            if (lane < ncnt) np = csrP[nbeg + lane];
        }
        // ---- consume staged batch from LDS
        float ax = 0.f, ay = 0.f, az = 0.f, aw = 0.f;
        int cnt = min(end - beg, 64);
        int jmax = (cnt + 7) >> 3;
        int j = 0;
        for (; j + 4 <= jmax; j += 4) {
            int2 e0 = ebase[(j + 0) * 8];
            int2 e1 = ebase[(j + 1) * 8];
            int2 e2 = ebase[(j + 2) * 8];
            int2 e3 = ebase[(j + 3) * 8];
            float4 a0 = xin[(size_t)e0.x * 64 + fbase];
            float4 a1 = xin[(size_t)e1.x * 64 + fbase];
            float4 a2 = xin[(size_t)e2.x * 64 + fbase];
            float4 a3 = xin[(size_t)e3.x * 64 + fbase];
            float w0 = __int_as_float(e0.y), w1 = __int_as_float(e1.y);
            float w2 = __int_as_float(e2.y), w3 = __int_as_float(e3.y);
            ax += w0 * a0.x + w1 * a1.x + w2 * a2.x + w3 * a3.x;
            ay += w0 * a0.y + w1 * a1.y + w2 * a2.y + w3 * a3.y;
            az += w0 * a0.z + w1 * a1.z + w2 * a2.z + w3 * a3.z;
            aw += w0 * a0.w + w1 * a1.w + w2 * a2.w + w3 * a3.w;
        }
        for (; j < jmax; ++j) {
            int2 e = ebase[j * 8];
            float4 a = xin[(size_t)e.x * 64 + fbase];
            float w = __int_as_float(e.y);
            ax += w * a.x; ay += w * a.y; az += w * a.z; aw += w * a.w;
        }
        // ---- rare spill batches (deg > 64): register + shfl path
        for (int eb = beg + 64; eb < end; eb += 64) {
            int scnt = end - eb;
            if (scnt > 64) scnt = 64;
            int myu = 0;
            float myw = 0.f;
            if (lane < scnt) {
                int2 p = csrP[eb + lane];
                myu = p.x;
                myw = __int_as_float(p.y);
            }
            int sjmax = (scnt + 7) >> 3;
            for (int sj = 0; sj < sjmax; ++sj) {
                int idx = sj * 8 + sub;
                int u = __shfl(myu, idx);
                float w = __shfl(myw, idx);
                float4 a = xin[(size_t)u * 64 + fbase];
                ax += w * a.x; ay += w * a.y; az += w * a.z; aw += w * a.w;
            }
        }
        // ---- reduce across the 8 subgroups (lane bits 3,4,5)
        ax += __shfl_xor(ax, 8);  ax += __shfl_xor(ax, 16); ax += __shfl_xor(ax, 32);
        ay += __shfl_xor(ay, 8);  ay += __shfl_xor(ay, 16); ay += __shfl_xor(ay, 32);
        az += __shfl_xor(az, 8);  az += __shfl_xor(az, 16); az += __shfl_xor(az, 32);
        aw += __shfl_xor(aw, 8);  aw += __shfl_xor(aw, 16); aw += __shfl_xor(aw, 32);
        if (sub == 0) {
            float si = sinv[node];
            float vx = si * ax, vy = si * ay, vz = si * az, vw = si * aw;
            ushort4 hi4 = make_ushort4(f2bf(vx), f2bf(vy), f2bf(vz), f2bf(vw));
            ushort4 lo4 = make_ushort4(f2bf(vx - bf2f(hi4.x)), f2bf(vy - bf2f(hi4.y)),
                                       f2bf(vz - bf2f(hi4.z)), f2bf(vw - bf2f(hi4.w)));
            size_t frag = ((size_t)(node >> 4) * 16 + kstepg) * 2;
            size_t addr = frag * 512 + ((node & 15) + (sl >> 1) * 16) * 8 + (sl & 1) * 4;
            *(ushort4*)&aggPk[addr] = hi4;
            *(ushort4*)&aggPk[addr + 512] = lo4;
        }
        // ---- commit prefetched batch (after all LDS reads of current batch)
        if (next < lim) elds[wave][lane] = np;
        beg = nbeg;
        end = nend;
        node = next;
    }
}

// ---------------------------------------------------------------- split-bf16 MFMA GEMM, LDS double-buffered
// C[M x 256] = (Ahi+Alo)[M x 512] @ W (+bias)(+relu), hi*hi + lo*hi + hi*lo.
// BM=80 (5 mtiles) x full 256 cols; 512 threads / 8 waves, wave = 2 ntiles.
// Double-buffer: global loads for ks+1 fly during MFMA of ks; ONE barrier/k-step.
template <int RELU>
__global__ __launch_bounds__(512) void gemm_mfma_kernel(
    const short8* __restrict__ Apk, const short8* __restrict__ Bpk,
    const float* __restrict__ bias, float* __restrict__ C, int M) {
    __shared__ short8 lds[2][42][64];   // 2 x 42 frags x 64 lanes x 16B = 84KB
    int tid = threadIdx.x;
    int lane = tid & 63;
    int wv = tid >> 6;     // 0..7
    int mt0 = blockIdx.x * 5;
    int m0 = blockIdx.x * 80;
    if (m0 >= M) return;
    int nt0 = wv * 2;
    int col0 = wv * 32;
    int frow = lane & 15;

    // slot decomposition for staging (6 slots/thread, last partially used)
    int sf[6], sln[6];
    bool sv[6];
    #pragma unroll
    for (int r = 0; r < 6; ++r) {
        int s = r * 512 + tid;
        sv[r] = s < 2688;
        sf[r] = s >> 6;
        sln[r] = s & 63;
    }
    auto gaddr = [&](int f, int l, int ks) -> size_t {
        if (f < 10) {
            return ((size_t)(mt0 + (f >> 1)) * 16 + ks) * 128 + (f & 1) * 64 + l;
        } else {
            int q = f - 10;
            return ((size_t)(q >> 1) * 16 + ks) * 128 + (q & 1) * 64 + l;
        }
    };

    f32x4 acc[5][2];
    #pragma unroll
    for (int fr = 0; fr < 5; ++fr)
        #pragma unroll
        for (int fc = 0; fc < 2; ++fc)
            acc[fr][fc] = (f32x4){0.f, 0.f, 0.f, 0.f};

    // prologue: stage ks=0
    short8 stg[6];
    #pragma unroll
    for (int r = 0; r < 6; ++r)
        if (sv[r]) stg[r] = (sf[r] < 10 ? Apk : Bpk)[gaddr(sf[r], sln[r], 0)];
    #pragma unroll
    for (int r = 0; r < 6; ++r)
        if (sv[r]) lds[0][sf[r]][sln[r]] = stg[r];
    __syncthreads();

    int cur = 0;
    for (int ks = 0; ks < 16; ++ks) {
        // issue next k-step's global loads (fly during MFMA below)
        if (ks + 1 < 16) {
            #pragma unroll
            for (int r = 0; r < 6; ++r)
                if (sv[r]) stg[r] = (sf[r] < 10 ? Apk : Bpk)[gaddr(sf[r], sln[r], ks + 1)];
        }
        // compute from lds[cur]
        short8 bh[2], bl[2];
        #pragma unroll
        for (int fc = 0; fc < 2; ++fc) {
            bh[fc] = lds[cur][10 + (nt0 + fc) * 2 + 0][lane];
            bl[fc] = lds[cur][10 + (nt0 + fc) * 2 + 1][lane];
        }
        #pragma unroll
        for (int fr = 0; fr < 5; ++fr) {
            short8 ah = lds[cur][fr * 2 + 0][lane];
            short8 al = lds[cur][fr * 2 + 1][lane];
            #pragma unroll
            for (int fc = 0; fc < 2; ++fc) {
                acc[fr][fc] = __builtin_amdgcn_mfma_f32_16x16x32_bf16(ah, bh[fc], acc[fr][fc], 0, 0, 0);
                acc[fr][fc] = __builtin_amdgcn_mfma_f32_16x16x32_bf16(al, bh[fc], acc[fr][fc], 0, 0, 0);
                acc[fr][fc] = __builtin_amdgcn_mfma_f32_16x16x32_bf16(ah, bl[fc], acc[fr][fc], 0, 0, 0);
            }
        }
        // write next buffer, single barrier
        if (ks + 1 < 16) {
            #pragma unroll
            for (int r = 0; r < 6; ++r)
                if (sv[r]) lds[cur ^ 1][sf[r]][sln[r]] = stg[r];
            __syncthreads();
            cur ^= 1;
        }
    }

    #pragma unroll
    for (int fr = 0; fr < 5; ++fr)
        #pragma unroll
        for (int fc = 0; fc < 2; ++fc) {
            int c = col0 + fc * 16 + frow;
            float bc = bias[c];
            int rb = m0 + fr * 16 + (lane >> 4) * 4;
            #pragma unroll
            for (int j = 0; j < 4; ++j) {
                int r = rb + j;
                if (r < M) {
                    float v = acc[fr][fc][j] + bc;
                    if (RELU) v = fmaxf(v, 0.f);
                    C[(size_t)r * 256 + c] = v;
                }
            }
        }
}

// ---------------------------------------------------------------- launch
extern "C" void kernel_launch(void* const* d_in, const int* in_sizes, int n_in,
                              void* d_out, int out_size, void* d_ws, size_t ws_size,
                              hipStream_t stream) {
    const float* x   = (const float*)d_in[0];
    const int* sS    = (const int*)d_in[1];
    const int* dS    = (const int*)d_in[2];
    const int* sU    = (const int*)d_in[3];
    const int* dU    = (const int*)d_in[4];
    const float* W1s = (const float*)d_in[5];
    const float* b1s = (const float*)d_in[6];
    const float* W1u = (const float*)d_in[7];
    const float* b1u = (const float*)d_in[8];
    const float* W2s = (const float*)d_in[9];
    const float* b2s = (const float*)d_in[10];
    const float* W2u = (const float*)d_in[11];
    const float* b2u = (const float*)d_in[12];
    float* out = (float*)d_out;

    const int n  = in_sizes[0] / 256;
    const int Es = in_sizes[1];
    const int Eu = in_sizes[3];
    const int NB = (n + SCHUNK - 1) / SCHUNK;
    const int gemmGrid = (n + 79) / 80;
    const size_t AGG_BYTES = (size_t)((n + 15) / 16 + 16) * 16 * 2 * 512 * 2;
    const size_t BPK_BYTES = (size_t)16 * 16 * 2 * 512 * 2;

    auto plan = [&](int nb) -> size_t {
        size_t t = 0;
        auto add = [&](size_t b) { t = (t + 255) & ~(size_t)255; t += b; };
        add((size_t)2 * nb * n * 4);            // histG
        add((size_t)2 * nb * n * 4);            // offsG
        add((size_t)(n + 1) * 4); add((size_t)(n + 1) * 4);
        add((size_t)n * 4); add((size_t)n * 4); add((size_t)n * 4); add((size_t)n * 4);
        add((size_t)n * 4); add((size_t)n * 4); // degIn
        add(256 * 4); add(256 * 4);
        add((size_t)2 * NB * 4);
        add((size_t)Es * 8); add((size_t)Eu * 8);
        add(2 * BPK_BYTES);
        add(AGG_BYTES);
        add((size_t)n * 256 * 4);               // h
        return t;
    };
    const int nblk = (plan(128) <= ws_size) ? 128 : 32;

    char* ws = (char*)d_ws;
    size_t off = 0;
    auto alloc = [&](size_t bytes) -> void* {
        off = (off + 255) & ~(size_t)255;
        void* p = ws + off;
        off += bytes;
        return p;
    };

    unsigned int* histG = (unsigned int*)alloc((size_t)2 * nblk * n * 4);
    int* offsG   = (int*)alloc((size_t)2 * nblk * n * 4);
    int* rpS     = (int*)alloc((size_t)(n + 1) * 4);
    int* rpU     = (int*)alloc((size_t)(n + 1) * 4);
    float* sOutS = (float*)alloc((size_t)n * 4);
    float* sInS  = (float*)alloc((size_t)n * 4);
    float* sOutU = (float*)alloc((size_t)n * 4);
    float* sInU  = (float*)alloc((size_t)n * 4);
    int* degInS  = (int*)alloc((size_t)n * 4);
    int* degInU  = (int*)alloc((size_t)n * 4);
    float* bsum1 = (float*)alloc(256 * 4);
    float* bsum2 = (float*)alloc(256 * 4);
    int* bsumBlk = (int*)alloc((size_t)2 * NB * 4);
    int2* csrPS  = (int2*)alloc((size_t)Es * 8);
    int2* csrPU  = (int2*)alloc((size_t)Eu * 8);
    unsigned short* Bpk1 = (unsigned short*)alloc(2 * BPK_BYTES);
    unsigned short* Bpk2 = Bpk1 + BPK_BYTES / 2;
    unsigned short* aggPk = (unsigned short*)alloc(AGG_BYTES);
    float* h     = (float*)alloc((size_t)n * 256 * 4);

    // ---- preprocessing (no global atomics)
    bias_sum_kernel<<<1, 256, 0, stream>>>(b1s, b1u, b2s, b2u, bsum1, bsum2);
    wprep_kernel<<<dim3(512, 2), 256, 0, stream>>>(W1s, W1u, W2s, W2u, Bpk1, Bpk2);
    dim3 hg(nblk, 2);
    hist_kernel<<<hg, 256, 0, stream>>>(sS, dS, sU, dU, Es, Eu, n, nblk, histG);
    dim3 tg((n + 255) / 256, 2);
    totals_kernel<<<tg, 256, 0, stream>>>(histG, n, nblk, sOutS, sInS, sOutU, sInU,
                                          degInS, degInU);
    dim3 sg(NB, 2);
    scan_part_kernel<<<sg, 256, 0, stream>>>(degInS, degInU, n, NB, bsumBlk);
    scan_mid_kernel<<<1, 64, 0, stream>>>(bsumBlk, NB, rpS, rpU, n);
    scan_final_kernel<<<sg, 256, 0, stream>>>(degInS, degInU, bsumBlk, n, NB, rpS, rpU);
    offsets_kernel<<<tg, 256, 0, stream>>>(histG, rpS, rpU, n, nblk, offsG);
    csr_scatter_kernel<<<hg, 256, 0, stream>>>(sS, dS, sU, dU, Es, Eu, n, nblk, offsG,
                                               sOutS, sOutU, csrPS, csrPU);

    // ---- layers
    int chunks = (n + NPB - 1) / NPB;
    int pullGrid = NSLICE * 2 * chunks;
    const float4* x4 = (const float4*)x;
    const float4* h4 = (const float4*)h;
    const short8* A8 = (const short8*)aggPk;
    const short8* B81 = (const short8*)Bpk1;
    const short8* B82 = (const short8*)Bpk2;

    pull_slice_kernel<<<pullGrid, 256, 0, stream>>>(x4, csrPS, csrPU, rpS, rpU,
                                                    sInS, sInU, aggPk, n);
    gemm_mfma_kernel<1><<<gemmGrid, 512, 0, stream>>>(A8, B81, bsum1, h, n);
    pull_slice_kernel<<<pullGrid, 256, 0, stream>>>(h4, csrPS, csrPU, rpS, rpU,
                                                    sInS, sInU, aggPk, n);
    gemm_mfma_kernel<0><<<gemmGrid, 512, 0, stream>>>(A8, B82, bsum2, out, n);
}